// Round 10
// baseline (276.064 us; speedup 1.0000x reference)
//
#include <hip/hip_runtime.h>

typedef unsigned short u16;
typedef __attribute__((ext_vector_type(8))) short s8;   // 8 bf16 (4 VGPR) MFMA frag
typedef __attribute__((ext_vector_type(4))) float f4;   // 4 f32 acc frag

#define B_  8
#define C_  64
#define H_  128
#define W_  128
#define HW_ (H_*W_)
#define PITCH 72     // LDS shorts per pixel (144 B rows, 16B-aligned, uniform bank spread)
#define WSZ 36864    // elems of one transformed weight tensor [9][64][64]

// tile: 8 rows x 16 cols output, halo 10 x 18. Grid 1024 flat, block 512 (8 waves).
// Wave specialization: waves 0-3 stage+conv the A side (plain), waves 4-7 the B side
// (PAC). Both tiles stage in ONE window; convA || convB run concurrently -> per-wave
// serial path ~halves vs r7 (r9 proved blocks are already maximally overlapped, so
// the wall time follows the per-wave path). 2 blocks/CU x 8 waves = 16 waves/CU,
// same residency as r7 (r8's mistake avoided). XCD swizzle b=L&7 kept (r7: FETCH
// 126->36.8 MB). Empirical VGPR law: cap = 256/launch_bounds_arg2 (r1/r2/r5) ->
// (512,2) keeps cap 128.

// f32 -> bf16 bits, round-to-nearest-even (finite only)
static __device__ __forceinline__ u16 f2bu(float f) {
    union { float f; unsigned u; } c; c.f = f;
    unsigned u = c.u;
    u += 0x7fffu + ((u >> 16) & 1u);
    return (u16)(u >> 16);
}
static __device__ __forceinline__ float bu2f(u16 u) {
    union { unsigned u; float f; } c; c.u = ((unsigned)u) << 16; return c.f;
}

// ---------- weight transform: 4x [o][c][3][3] f32 -> [cid][p][o][c] bf16 ----------
__global__ __launch_bounds__(256) void wt_all(
    const float* __restrict__ w0, const float* __restrict__ w1,
    const float* __restrict__ w2, const float* __restrict__ w3,
    u16* __restrict__ dst)
{
    int idx = blockIdx.x*256 + threadIdx.x;            // 0..36863
    int cid = blockIdx.y;
    const float* w = (cid == 0) ? w0 : (cid == 1) ? w1 : (cid == 2) ? w2 : w3;
    int p = idx >> 12, o = (idx >> 6) & 63, c = idx & 63;
    dst[(size_t)cid*WSZ + idx] = f2bu(w[((size_t)o*64 + c)*9 + p]);
}

// ---------- staging: bf16 NHWC -> LDS [pix][ch] (stage 2 inputs); tl in [0,256) ----------
static __device__ __forceinline__ void stage_tile(
    u16* __restrict__ s_t, const u16* __restrict__ src, int b, int th0, int tw0, int tl)
{
    for (int i = tl; i < 10*18*8; i += 256) {
        int pix = i >> 3, ch = i & 7;
        int rr = pix / 18, ww = pix - rr*18;
        int gr = th0 + rr - 1, gw = tw0 + ww - 1;
        uint4 v = {0u,0u,0u,0u};
        if ((unsigned)gr < (unsigned)H_ && (unsigned)gw < (unsigned)W_)
            v = *(const uint4*)(src + ((size_t)b*HW_ + gr*W_ + gw)*64 + ch*8);
        *(uint4*)(&s_t[pix*PITCH + ch*8]) = v;
    }
}

// ---------- staging: f32 NCHW -> LDS [pix][ch] bf16 (stage 1 inputs); tl in [0,256) ----------
// task i in [0,320): cp = i&31 (channel pair), rr = i>>5 (halo row 0..9).
static __device__ __forceinline__ void stage_tile_f32(
    u16* __restrict__ s_t, const float* __restrict__ src, int b, int th0, int tw0, int tl)
{
    const bool lok = (tw0 != 0);         // wave-uniform edge flags
    const bool rok = (tw0 != W_ - 16);
    for (int i = tl; i < 320; i += 256) {
        const int cp = i & 31, rr = i >> 5;
        const int gr = th0 + rr - 1;
        const int c0 = cp * 2;
        float v0[18], v1[18];
        if ((unsigned)gr < (unsigned)H_) {
            const float* a0 = src + ((size_t)b*C_ + c0)*HW_ + (size_t)gr*W_ + tw0;
            const float* a1 = a0 + HW_;
            v0[0]  = lok ? a0[-1] : 0.f;
            v1[0]  = lok ? a1[-1] : 0.f;
#pragma unroll
            for (int g = 0; g < 4; ++g) {
                *(f4*)(v0 + 1 + g*4) = *(const f4*)(a0 + g*4);   // 16B-aligned
                *(f4*)(v1 + 1 + g*4) = *(const f4*)(a1 + g*4);
            }
            v0[17] = rok ? a0[16] : 0.f;
            v1[17] = rok ? a1[16] : 0.f;
        } else {
#pragma unroll
            for (int j = 0; j < 18; ++j) { v0[j] = 0.f; v1[j] = 0.f; }
        }
#pragma unroll
        for (int j = 0; j < 18; ++j) {
            unsigned pk = (unsigned)f2bu(v0[j]) | ((unsigned)f2bu(v1[j]) << 16);
            *(unsigned*)(&s_t[(rr*18 + j)*PITCH + c0]) = pk;
        }
    }
}

// conv core: D = sum_p [kern_p ⊙] W_p[32och,64c] x X_p[64c,64px], f32 acc, bias init.
// wave (wvM,wvN): och half wvM, pixel rows wvN*4+nf; frag maps verified (rounds 1/4/5).
template<bool PAC>
static __device__ __forceinline__ void conv_core(
    const u16* __restrict__ s_t, const float* __restrict__ s_k,
    const u16* __restrict__ w, const float* __restrict__ bias,
    f4 acc[2][4], int wvM, int wvN, int ln, int quad)
{
#pragma unroll
    for (int mf = 0; mf < 2; ++mf) {
        f4 bv;
#pragma unroll
        for (int r = 0; r < 4; ++r) bv[r] = bias[wvM*32 + mf*16 + quad*4 + r];
#pragma unroll
        for (int nf = 0; nf < 4; ++nf) acc[mf][nf] = bv;
    }

#pragma unroll
    for (int p = 0; p < 9; ++p) {
        const int dr = p / 3, dc = p - dr*3;
        s8 a[2][2];
#pragma unroll
        for (int mf = 0; mf < 2; ++mf)
#pragma unroll
            for (int kc = 0; kc < 2; ++kc)
                a[mf][kc] = *(const s8*)(w + (((size_t)p*64 + wvM*32 + mf*16 + ln)*64 + kc*32 + quad*8));
        s8 bfr[4][2];
#pragma unroll
        for (int nf = 0; nf < 4; ++nf) {
            const u16* base = &s_t[((wvN*4 + nf + dr)*18 + ln + dc)*PITCH];
#pragma unroll
            for (int kc = 0; kc < 2; ++kc)
                bfr[nf][kc] = *(const s8*)(base + kc*32 + quad*8);
        }
        if (PAC) {
            float kv[4];
#pragma unroll
            for (int nf = 0; nf < 4; ++nf)
                kv[nf] = s_k[p*128 + (wvN*4 + nf)*16 + ln];
#pragma unroll
            for (int mf = 0; mf < 2; ++mf)
#pragma unroll
                for (int nf = 0; nf < 4; ++nf) {
                    f4 d = {0.f, 0.f, 0.f, 0.f};
                    d = __builtin_amdgcn_mfma_f32_16x16x32_bf16(a[mf][0], bfr[nf][0], d, 0, 0, 0);
                    d = __builtin_amdgcn_mfma_f32_16x16x32_bf16(a[mf][1], bfr[nf][1], d, 0, 0, 0);
                    acc[mf][nf] += kv[nf] * d;
                }
        } else {
#pragma unroll
            for (int mf = 0; mf < 2; ++mf)
#pragma unroll
                for (int nf = 0; nf < 4; ++nf) {
                    acc[mf][nf] = __builtin_amdgcn_mfma_f32_16x16x32_bf16(a[mf][0], bfr[nf][0], acc[mf][nf], 0, 0, 0);
                    acc[mf][nf] = __builtin_amdgcn_mfma_f32_16x16x32_bf16(a[mf][1], bfr[nf][1], acc[mf][nf], 0, 0, 0);
                }
        }
    }
}

// epilogue: bf16 NHWC with relu (stage 1)
static __device__ __forceinline__ void store_t(
    u16* __restrict__ out, f4 acc[2][4], int b, int th0, int tw0,
    int wvM, int wvN, int ln, int quad)
{
#pragma unroll
    for (int mf = 0; mf < 2; ++mf)
#pragma unroll
        for (int nf = 0; nf < 4; ++nf) {
            f4 v = acc[mf][nf];
            ushort4 o;
            o.x = f2bu(fmaxf(v[0], 0.f)); o.y = f2bu(fmaxf(v[1], 0.f));
            o.z = f2bu(fmaxf(v[2], 0.f)); o.w = f2bu(fmaxf(v[3], 0.f));
            size_t pix = (size_t)b*HW_ + (th0 + wvN*4 + nf)*W_ + tw0 + ln;
            *(ushort4*)(out + pix*64 + wvM*32 + mf*16 + quad*4) = o;
        }
}

// epilogue: f32 NCHW out + residual read from f32 NCHW (stage 2; exact, coalesced)
static __device__ __forceinline__ void store_f(
    float* __restrict__ out, const float* __restrict__ resid,
    f4 acc[2][4], int b, int th0, int tw0, int wvM, int wvN, int ln, int quad)
{
#pragma unroll
    for (int mf = 0; mf < 2; ++mf)
#pragma unroll
        for (int nf = 0; nf < 4; ++nf) {
#pragma unroll
            for (int r = 0; r < 4; ++r) {
                int och = wvM*32 + mf*16 + quad*4 + r;
                size_t idx = ((size_t)b*C_ + och)*HW_ + (th0 + wvN*4 + nf)*W_ + tw0 + ln;
                out[idx] = acc[mf][nf][r] + resid[idx];
            }
        }
}

// ---------- fused stage (wave-specialized): ----------
// waves 0-3: stage s_tA(inA) -> convA (plain) -> storeA
// waves 4-7: stage s_tB(inB) -> convB (PAC)  -> storeB
// gauss(s_tA) by all 512 threads between the two barriers.
template<bool STAGE1>
__global__ __launch_bounds__(512, 2) void fused_stage(
    const float* __restrict__ inA_f, const float* __restrict__ inB_f,
    const u16* __restrict__ inA_t, const u16* __restrict__ inB_t,
    const u16* __restrict__ wA, const u16* __restrict__ wB,
    const float* __restrict__ biasA, const float* __restrict__ biasB,
    const float* __restrict__ residA_f, const float* __restrict__ residB_f,
    u16* __restrict__ outA_t, u16* __restrict__ outB_t,
    float* __restrict__ outA_f, float* __restrict__ outB_f)
{
    __shared__ u16   s_tA[10*18*PITCH];  // 25920 B (guide / A tile)
    __shared__ u16   s_tB[10*18*PITCH];  // 25920 B (B tile)
    __shared__ float s_k[9*128];         //  4608 B  (56448 B total; 2 blk/CU = 16 waves/CU)

    const int t    = threadIdx.x;        // 0..511
    // XCD swizzle: round-robin dispatch => xcd = L&7 = batch image.
    const int L    = blockIdx.x;         // 0..1023
    const int b    = L & 7;
    const int tw0  = ((L >> 3) & 7) * 16;
    const int th0  = (L >> 6) * 8;
    const int grp  = t >> 8;             // 0 = A side, 1 = B side (wave-uniform)
    const int tl   = t & 255;
    const int wv   = tl >> 6;            // wave within group (0..3)
    const int wvM  = wv >> 1;            // och half
    const int wvN  = wv & 1;             // pixel-row half
    const int lane = tl & 63;
    const int ln   = lane & 15;
    const int quad = lane >> 4;

    // ---- phase 1: both tiles staged concurrently, one window ----
    if (STAGE1) {
        if (grp == 0) stage_tile_f32(s_tA, inA_f, b, th0, tw0, tl);
        else          stage_tile_f32(s_tB, inB_f, b, th0, tw0, tl);
    } else {
        if (grp == 0) stage_tile(s_tA, inA_t, b, th0, tw0, tl);
        else          stage_tile(s_tB, inB_t, b, th0, tw0, tl);
    }
    __syncthreads();

    // ---- phase 2: gaussian kernel from s_tA, split over ALL 512 threads ----
    // pixel = t&127, tap-quarter q = t>>7: q0={0,1} q1={2,3} q2={4,5} q3={6,7,8}.
    {
        const int px = t & 127;
        const int q  = t >> 7;           // 0..3
        const int p0 = q * 2;
        const int np = (q == 3) ? 3 : 2;
        const int py = px >> 4, pxc = px & 15;
        float d2[3];
#pragma unroll
        for (int k = 0; k < 3; ++k) d2[k] = 0.f;
        const u16* cb = &s_tA[((py+1)*18 + (pxc+1))*PITCH];
#pragma unroll 1
        for (int co = 0; co < 8; ++co) {
            s8 c8 = *(const s8*)(cb + co*8);
            float cf[8];
#pragma unroll
            for (int j = 0; j < 8; ++j) cf[j] = bu2f((u16)c8[j]);
#pragma unroll
            for (int k = 0; k < 3; ++k) {
                if (k < np) {
                    int p = p0 + k;
                    int dr = p / 3, dc = p - dr*3;
                    s8 n8 = *(const s8*)(&s_tA[((py + dr)*18 + pxc + dc)*PITCH + co*8]);
#pragma unroll
                    for (int j = 0; j < 8; ++j) {
                        float d = bu2f((u16)n8[j]) - cf[j];
                        d2[k] += d * d;
                    }
                }
            }
        }
#pragma unroll
        for (int k = 0; k < 3; ++k)
            if (k < np) s_k[(p0+k)*128 + px] = __expf(-0.5f * d2[k]);
    }
    __syncthreads();

    // ---- phase 3: convA || convB, concurrent on the CU ----
    if (grp == 0) {
        f4 acc[2][4];
        conv_core<false>(s_tA, nullptr, wA, biasA, acc, wvM, wvN, ln, quad);
        if (STAGE1) store_t(outA_t, acc, b, th0, tw0, wvM, wvN, ln, quad);
        else        store_f(outA_f, residA_f, acc, b, th0, tw0, wvM, wvN, ln, quad);
    } else {
        f4 acc[2][4];
        conv_core<true>(s_tB, s_k, wB, biasB, acc, wvM, wvN, ln, quad);
        if (STAGE1) store_t(outB_t, acc, b, th0, tw0, wvM, wvN, ln, quad);
        else        store_f(outB_f, residB_f, acc, b, th0, tw0, wvM, wvN, ln, quad);
    }
}

extern "C" void kernel_launch(void* const* d_in, const int* in_sizes, int n_in,
                              void* d_out, int out_size, void* d_ws, size_t ws_size,
                              hipStream_t stream)
{
    const float* x      = (const float*)d_in[0];
    const float* edge   = (const float*)d_in[1];
    const float* w_pac1 = (const float*)d_in[2];
    const float* b_pac1 = (const float*)d_in[3];
    const float* w_pac2 = (const float*)d_in[4];
    const float* b_pac2 = (const float*)d_in[5];
    const float* w_e1   = (const float*)d_in[6];
    const float* b_e1   = (const float*)d_in[7];
    const float* w_e2   = (const float*)d_in[8];
    const float* b_e2   = (const float*)d_in[9];

    float* out_sr   = (float*)d_out;
    float* out_edge = out_sr + (size_t)B_*C_*HW_;

    const size_t NT = (size_t)B_*HW_*64;
    // ws: stage-1 outputs (bf16 NHWC) + transformed weights. No input copies needed.
    u16* res_edge1_t = (u16*)d_ws;
    u16* res_sr1_t   = res_edge1_t + NT;
    u16* w_t         = res_sr1_t + NT;    // [4][9][64][64]: 0=e1, 1=pac1, 2=e2, 3=pac2

    wt_all<<<dim3(144, 4), dim3(256), 0, stream>>>(w_e1, w_pac1, w_e2, w_pac2, w_t);

    // stage 1: gauss(edge)=kern1 (LDS-only) + conv_e1(edge) + pac1(x), staged from f32 NCHW
    fused_stage<true ><<<dim3(1024), dim3(512), 0, stream>>>(
        edge, x, nullptr, nullptr,
        w_t + 0*WSZ, w_t + 1*WSZ, b_e1, b_pac1,
        nullptr, nullptr, res_edge1_t, res_sr1_t, nullptr, nullptr);
    // stage 2: gauss(res_edge1)=kern2 + conv_e2(res_edge1)+edge_resid + pac2(res_sr1)+x_resid
    fused_stage<false><<<dim3(1024), dim3(512), 0, stream>>>(
        nullptr, nullptr, res_edge1_t, res_sr1_t,
        w_t + 2*WSZ, w_t + 3*WSZ, b_e2, b_pac2,
        edge, x, nullptr, nullptr, out_edge, out_sr);
}

// Round 11
// 222.021 us; speedup vs baseline: 1.2434x; 1.2434x over previous
//
#include <hip/hip_runtime.h>
#include <hip/hip_cooperative_groups.h>

typedef unsigned short u16;
typedef __attribute__((ext_vector_type(8))) short s8;   // 8 bf16 (4 VGPR) MFMA frag
typedef __attribute__((ext_vector_type(4))) float f4;   // 4 f32 acc frag

#define B_  8
#define C_  64
#define H_  128
#define W_  128
#define HW_ (H_*W_)
#define PITCH 72     // LDS shorts per pixel (144 B rows, 16B-aligned, uniform bank spread)
#define WSZ 36864    // elems of one transformed weight tensor [9][64][64]

// tile: 8 rows x 16 cols output, halo 10 x 18. Grid 1024 flat, 256 threads.
// XCD swizzle: b = L&7 -> xcd == batch image (verified r7: FETCH 126->36.8 MB).
// r8/r9/r10 all refuted intra-kernel overlap restructures; r7's shape is the
// per-kernel optimum. Remaining cost: ~75us of inter-dispatch overhead across
// 3 kernels. This round: ONE cooperative kernel (wt prologue -> grid.sync ->
// stage1 -> grid.sync -> stage2). 1024 blocks = 4/CU x 256 CU exactly resident
// (30.5KB LDS, VGPR<=128). Fallback to the r7 3-kernel path if occupancy < 4.

// f32 -> bf16 bits, round-to-nearest-even (finite only)
static __device__ __forceinline__ u16 f2bu(float f) {
    union { float f; unsigned u; } c; c.f = f;
    unsigned u = c.u;
    u += 0x7fffu + ((u >> 16) & 1u);
    return (u16)(u >> 16);
}
static __device__ __forceinline__ float bu2f(u16 u) {
    union { unsigned u; float f; } c; c.u = ((unsigned)u) << 16; return c.f;
}

// ---------- weight transform: 4x [o][c][3][3] f32 -> [cid][p][o][c] bf16 ----------
__global__ __launch_bounds__(256) void wt_all(
    const float* __restrict__ w0, const float* __restrict__ w1,
    const float* __restrict__ w2, const float* __restrict__ w3,
    u16* __restrict__ dst)
{
    int idx = blockIdx.x*256 + threadIdx.x;            // 0..36863
    int cid = blockIdx.y;
    const float* w = (cid == 0) ? w0 : (cid == 1) ? w1 : (cid == 2) ? w2 : w3;
    int p = idx >> 12, o = (idx >> 6) & 63, c = idx & 63;
    dst[(size_t)cid*WSZ + idx] = f2bu(w[((size_t)o*64 + c)*9 + p]);
}

// ---------- staging: bf16 NHWC -> LDS [pix][ch] (stage 2 inputs) ----------
static __device__ __forceinline__ void stage_tile(
    u16* __restrict__ s_t, const u16* __restrict__ src, int b, int th0, int tw0, int t)
{
    for (int i = t; i < 10*18*8; i += 256) {
        int pix = i >> 3, ch = i & 7;
        int rr = pix / 18, ww = pix - rr*18;
        int gr = th0 + rr - 1, gw = tw0 + ww - 1;
        uint4 v = {0u,0u,0u,0u};
        if ((unsigned)gr < (unsigned)H_ && (unsigned)gw < (unsigned)W_)
            v = *(const uint4*)(src + ((size_t)b*HW_ + gr*W_ + gw)*64 + ch*8);
        *(uint4*)(&s_t[pix*PITCH + ch*8]) = v;
    }
}

// ---------- staging: f32 NCHW -> LDS [pix][ch] bf16 (stage 1 inputs) ----------
// task i in [0,320): cp = i&31 (channel pair), rr = i>>5 (halo row 0..9).
static __device__ __forceinline__ void stage_tile_f32(
    u16* __restrict__ s_t, const float* __restrict__ src, int b, int th0, int tw0, int t)
{
    const bool lok = (tw0 != 0);         // wave-uniform edge flags
    const bool rok = (tw0 != W_ - 16);
    for (int i = t; i < 320; i += 256) {
        const int cp = i & 31, rr = i >> 5;
        const int gr = th0 + rr - 1;
        const int c0 = cp * 2;
        float v0[18], v1[18];
        if ((unsigned)gr < (unsigned)H_) {
            const float* a0 = src + ((size_t)b*C_ + c0)*HW_ + (size_t)gr*W_ + tw0;
            const float* a1 = a0 + HW_;
            v0[0]  = lok ? a0[-1] : 0.f;
            v1[0]  = lok ? a1[-1] : 0.f;
#pragma unroll
            for (int g = 0; g < 4; ++g) {
                *(f4*)(v0 + 1 + g*4) = *(const f4*)(a0 + g*4);   // 16B-aligned
                *(f4*)(v1 + 1 + g*4) = *(const f4*)(a1 + g*4);
            }
            v0[17] = rok ? a0[16] : 0.f;
            v1[17] = rok ? a1[16] : 0.f;
        } else {
#pragma unroll
            for (int j = 0; j < 18; ++j) { v0[j] = 0.f; v1[j] = 0.f; }
        }
#pragma unroll
        for (int j = 0; j < 18; ++j) {
            unsigned pk = (unsigned)f2bu(v0[j]) | ((unsigned)f2bu(v1[j]) << 16);
            *(unsigned*)(&s_t[(rr*18 + j)*PITCH + c0]) = pk;
        }
    }
}

// conv core: D = sum_p [kern_p ⊙] W_p[32och,64c] x X_p[64c,64px], f32 acc, bias init.
// wave (wvM,wvN): och half wvM, pixel rows wvN*4+nf; frag maps verified (rounds 1/4/5).
template<bool PAC>
static __device__ __forceinline__ void conv_core(
    const u16* __restrict__ s_t, const float* __restrict__ s_k,
    const u16* __restrict__ w, const float* __restrict__ bias,
    f4 acc[2][4], int wvM, int wvN, int ln, int quad)
{
#pragma unroll
    for (int mf = 0; mf < 2; ++mf) {
        f4 bv;
#pragma unroll
        for (int r = 0; r < 4; ++r) bv[r] = bias[wvM*32 + mf*16 + quad*4 + r];
#pragma unroll
        for (int nf = 0; nf < 4; ++nf) acc[mf][nf] = bv;
    }

#pragma unroll
    for (int p = 0; p < 9; ++p) {
        const int dr = p / 3, dc = p - dr*3;
        s8 a[2][2];
#pragma unroll
        for (int mf = 0; mf < 2; ++mf)
#pragma unroll
            for (int kc = 0; kc < 2; ++kc)
                a[mf][kc] = *(const s8*)(w + (((size_t)p*64 + wvM*32 + mf*16 + ln)*64 + kc*32 + quad*8));
        s8 bfr[4][2];
#pragma unroll
        for (int nf = 0; nf < 4; ++nf) {
            const u16* base = &s_t[((wvN*4 + nf + dr)*18 + ln + dc)*PITCH];
#pragma unroll
            for (int kc = 0; kc < 2; ++kc)
                bfr[nf][kc] = *(const s8*)(base + kc*32 + quad*8);
        }
        if (PAC) {
            float kv[4];
#pragma unroll
            for (int nf = 0; nf < 4; ++nf)
                kv[nf] = s_k[p*128 + (wvN*4 + nf)*16 + ln];
#pragma unroll
            for (int mf = 0; mf < 2; ++mf)
#pragma unroll
                for (int nf = 0; nf < 4; ++nf) {
                    f4 d = {0.f, 0.f, 0.f, 0.f};
                    d = __builtin_amdgcn_mfma_f32_16x16x32_bf16(a[mf][0], bfr[nf][0], d, 0, 0, 0);
                    d = __builtin_amdgcn_mfma_f32_16x16x32_bf16(a[mf][1], bfr[nf][1], d, 0, 0, 0);
                    acc[mf][nf] += kv[nf] * d;
                }
        } else {
#pragma unroll
            for (int mf = 0; mf < 2; ++mf)
#pragma unroll
                for (int nf = 0; nf < 4; ++nf) {
                    acc[mf][nf] = __builtin_amdgcn_mfma_f32_16x16x32_bf16(a[mf][0], bfr[nf][0], acc[mf][nf], 0, 0, 0);
                    acc[mf][nf] = __builtin_amdgcn_mfma_f32_16x16x32_bf16(a[mf][1], bfr[nf][1], acc[mf][nf], 0, 0, 0);
                }
        }
    }
}

// epilogue: bf16 NHWC with relu (stage 1)
static __device__ __forceinline__ void store_t(
    u16* __restrict__ out, f4 acc[2][4], int b, int th0, int tw0,
    int wvM, int wvN, int ln, int quad)
{
#pragma unroll
    for (int mf = 0; mf < 2; ++mf)
#pragma unroll
        for (int nf = 0; nf < 4; ++nf) {
            f4 v = acc[mf][nf];
            ushort4 o;
            o.x = f2bu(fmaxf(v[0], 0.f)); o.y = f2bu(fmaxf(v[1], 0.f));
            o.z = f2bu(fmaxf(v[2], 0.f)); o.w = f2bu(fmaxf(v[3], 0.f));
            size_t pix = (size_t)b*HW_ + (th0 + wvN*4 + nf)*W_ + tw0 + ln;
            *(ushort4*)(out + pix*64 + wvM*32 + mf*16 + quad*4) = o;
        }
}

// epilogue: f32 NCHW out + residual read from f32 NCHW (stage 2; exact, coalesced)
static __device__ __forceinline__ void store_f(
    float* __restrict__ out, const float* __restrict__ resid,
    f4 acc[2][4], int b, int th0, int tw0, int wvM, int wvN, int ln, int quad)
{
#pragma unroll
    for (int mf = 0; mf < 2; ++mf)
#pragma unroll
        for (int nf = 0; nf < 4; ++nf) {
#pragma unroll
            for (int r = 0; r < 4; ++r) {
                int och = wvM*32 + mf*16 + quad*4 + r;
                size_t idx = ((size_t)b*C_ + och)*HW_ + (th0 + wvN*4 + nf)*W_ + tw0 + ln;
                out[idx] = acc[mf][nf][r] + resid[idx];
            }
        }
}

// ---------- one fused stage body (r7 structure, verified) ----------
template<bool STAGE1>
static __device__ __forceinline__ void phase_body(
    const float* __restrict__ inA_f, const float* __restrict__ inB_f,
    const u16* __restrict__ inA_t, const u16* __restrict__ inB_t,
    const u16* __restrict__ wA, const u16* __restrict__ wB,
    const float* __restrict__ biasA, const float* __restrict__ biasB,
    const float* __restrict__ residA_f, const float* __restrict__ residB_f,
    u16* __restrict__ outA_t, u16* __restrict__ outB_t,
    float* __restrict__ outA_f, float* __restrict__ outB_f,
    u16* __restrict__ s_t, float* __restrict__ s_k)
{
    const int t    = threadIdx.x;
    const int L    = blockIdx.x;         // 0..1023; xcd = L&7 = batch image
    const int b    = L & 7;
    const int tw0  = ((L >> 3) & 7) * 16;
    const int th0  = (L >> 6) * 8;
    const int wv   = t >> 6;
    const int wvM  = wv >> 1;            // och half (0..1)
    const int wvN  = wv & 1;             // pixel-row half (0..1)
    const int lane = t & 63;
    const int ln   = lane & 15;
    const int quad = lane >> 4;

    // ---- phase 1: stage guide/inA tile ----
    if (STAGE1) stage_tile_f32(s_t, inA_f, b, th0, tw0, t);
    else        stage_tile    (s_t, inA_t, b, th0, tw0, t);
    __syncthreads();

    // ---- phase 2a: gaussian kernel from inA tile -> s_k ----
    // 128 pixels, 256 threads: thread owns pixel (t&127) and taps p0..p0+np-1.
    {
        const int px   = t & 127;
        const int half = t >> 7;
        const int p0   = half ? 5 : 0;
        const int np   = half ? 4 : 5;
        const int py   = px >> 4, pxc = px & 15;
        float d2[5];
#pragma unroll
        for (int k = 0; k < 5; ++k) d2[k] = 0.f;
        const u16* cb = &s_t[((py+1)*18 + (pxc+1))*PITCH];
#pragma unroll 1
        for (int co = 0; co < 8; ++co) {
            s8 c8 = *(const s8*)(cb + co*8);
            float cf[8];
#pragma unroll
            for (int j = 0; j < 8; ++j) cf[j] = bu2f((u16)c8[j]);
#pragma unroll
            for (int k = 0; k < 5; ++k) {
                if (k < np) {
                    int p = p0 + k;
                    int dr = p / 3, dc = p - dr*3;
                    s8 n8 = *(const s8*)(&s_t[((py + dr)*18 + pxc + dc)*PITCH + co*8]);
#pragma unroll
                    for (int j = 0; j < 8; ++j) {
                        float d = bu2f((u16)n8[j]) - cf[j];
                        d2[k] += d * d;
                    }
                }
            }
        }
#pragma unroll
        for (int k = 0; k < 5; ++k)
            if (k < np) s_k[(p0+k)*128 + px] = __expf(-0.5f * d2[k]);
    }

    // ---- phase 2b: convA (plain) on inA tile ----
    {
        f4 acc[2][4];
        conv_core<false>(s_t, nullptr, wA, biasA, acc, wvM, wvN, ln, quad);
        if (STAGE1) store_t(outA_t, acc, b, th0, tw0, wvM, wvN, ln, quad);
        else        store_f(outA_f, residA_f, acc, b, th0, tw0, wvM, wvN, ln, quad);
    }

    // ---- phase 3: restage with inB tile (also orders s_k writes before reads) ----
    __syncthreads();
    if (STAGE1) stage_tile_f32(s_t, inB_f, b, th0, tw0, t);
    else        stage_tile    (s_t, inB_t, b, th0, tw0, t);
    __syncthreads();

    // ---- phase 4: convB (PAC with s_k) on inB tile ----
    {
        f4 acc[2][4];
        conv_core<true>(s_t, s_k, wB, biasB, acc, wvM, wvN, ln, quad);
        if (STAGE1) store_t(outB_t, acc, b, th0, tw0, wvM, wvN, ln, quad);
        else        store_f(outB_f, residB_f, acc, b, th0, tw0, wvM, wvN, ln, quad);
    }
}

// ---------- fallback path: r7's standalone stage kernel ----------
template<bool STAGE1>
__global__ __launch_bounds__(256, 2) void fused_stage(
    const float* __restrict__ inA_f, const float* __restrict__ inB_f,
    const u16* __restrict__ inA_t, const u16* __restrict__ inB_t,
    const u16* __restrict__ wA, const u16* __restrict__ wB,
    const float* __restrict__ biasA, const float* __restrict__ biasB,
    const float* __restrict__ residA_f, const float* __restrict__ residB_f,
    u16* __restrict__ outA_t, u16* __restrict__ outB_t,
    float* __restrict__ outA_f, float* __restrict__ outB_f)
{
    __shared__ u16   s_t[10*18*PITCH];   // 25920 B
    __shared__ float s_k[9*128];         //  4608 B  (30528 B total)
    phase_body<STAGE1>(inA_f, inB_f, inA_t, inB_t, wA, wB, biasA, biasB,
                       residA_f, residB_f, outA_t, outB_t, outA_f, outB_f, s_t, s_k);
}

// ---------- the single cooperative kernel: wt -> sync -> stage1 -> sync -> stage2 ----------
__global__ __launch_bounds__(256, 2) void fused_all(
    const float* __restrict__ x, const float* __restrict__ edge,
    const float* __restrict__ w_pac1, const float* __restrict__ b_pac1,
    const float* __restrict__ w_pac2, const float* __restrict__ b_pac2,
    const float* __restrict__ w_e1,  const float* __restrict__ b_e1,
    const float* __restrict__ w_e2,  const float* __restrict__ b_e2,
    u16* __restrict__ res_edge1_t, u16* __restrict__ res_sr1_t,
    u16* __restrict__ w_t, float* __restrict__ out_sr, float* __restrict__ out_edge)
{
    __shared__ u16   s_t[10*18*PITCH];   // 25920 B
    __shared__ float s_k[9*128];         //  4608 B  (30528 B total)

    cooperative_groups::grid_group grid = cooperative_groups::this_grid();

    // ---- prologue: weight transform, 1 elem/thread (147456 < 262144 threads) ----
    {
        int gid = blockIdx.x*256 + threadIdx.x;
        if (gid < 4*WSZ) {
            int cid = gid / WSZ;                        // 0=e1, 1=pac1, 2=e2, 3=pac2
            int idx = gid - cid*WSZ;
            const float* w = (cid == 0) ? w_e1 : (cid == 1) ? w_pac1
                           : (cid == 2) ? w_e2 : w_pac2;
            int p = idx >> 12, o = (idx >> 6) & 63, c = idx & 63;
            w_t[(size_t)cid*WSZ + idx] = f2bu(w[((size_t)o*64 + c)*9 + p]);
        }
    }
    __threadfence();
    grid.sync();

    // ---- stage 1: gauss(edge) + conv_e1(edge) + pac1(x) -> bf16 NHWC res tiles ----
    phase_body<true>(edge, x, nullptr, nullptr,
                     w_t + 0*WSZ, w_t + 1*WSZ, b_e1, b_pac1,
                     nullptr, nullptr, res_edge1_t, res_sr1_t, nullptr, nullptr,
                     s_t, s_k);
    __threadfence();
    grid.sync();

    // ---- stage 2: gauss(res_edge1) + conv_e2+edge_resid + pac2+x_resid -> f32 NCHW ----
    phase_body<false>(nullptr, nullptr, res_edge1_t, res_sr1_t,
                      w_t + 2*WSZ, w_t + 3*WSZ, b_e2, b_pac2,
                      edge, x, nullptr, nullptr, out_edge, out_sr,
                      s_t, s_k);
}

extern "C" void kernel_launch(void* const* d_in, const int* in_sizes, int n_in,
                              void* d_out, int out_size, void* d_ws, size_t ws_size,
                              hipStream_t stream)
{
    const float* x      = (const float*)d_in[0];
    const float* edge   = (const float*)d_in[1];
    const float* w_pac1 = (const float*)d_in[2];
    const float* b_pac1 = (const float*)d_in[3];
    const float* w_pac2 = (const float*)d_in[4];
    const float* b_pac2 = (const float*)d_in[5];
    const float* w_e1   = (const float*)d_in[6];
    const float* b_e1   = (const float*)d_in[7];
    const float* w_e2   = (const float*)d_in[8];
    const float* b_e2   = (const float*)d_in[9];

    float* out_sr   = (float*)d_out;
    float* out_edge = out_sr + (size_t)B_*C_*HW_;

    const size_t NT = (size_t)B_*HW_*64;
    u16* res_edge1_t = (u16*)d_ws;
    u16* res_sr1_t   = res_edge1_t + NT;
    u16* w_t         = res_sr1_t + NT;    // [4][9][64][64]: 0=e1, 1=pac1, 2=e2, 3=pac2

    // One-time: can fused_all run 4 blocks/CU (required for the 1024-block
    // cooperative launch)? If regalloc pushed VGPR > 128 this reports < 4.
    static int coop_ok = -1;
    if (coop_ok < 0) {
        int nb = 0;
        hipError_t e = hipOccupancyMaxActiveBlocksPerMultiprocessor(
            &nb, reinterpret_cast<const void*>(&fused_all), 256, 0);
        coop_ok = (e == hipSuccess && nb >= 4) ? 1 : 0;
    }

    if (coop_ok) {
        void* args[] = {
            (void*)&x, (void*)&edge,
            (void*)&w_pac1, (void*)&b_pac1, (void*)&w_pac2, (void*)&b_pac2,
            (void*)&w_e1,  (void*)&b_e1,  (void*)&w_e2,  (void*)&b_e2,
            (void*)&res_edge1_t, (void*)&res_sr1_t, (void*)&w_t,
            (void*)&out_sr, (void*)&out_edge
        };
        hipLaunchCooperativeKernel(reinterpret_cast<const void*>(&fused_all),
                                   dim3(1024), dim3(256), args, 0, stream);
    } else {
        // fallback: proven r7 3-kernel path
        wt_all<<<dim3(144, 4), dim3(256), 0, stream>>>(w_e1, w_pac1, w_e2, w_pac2, w_t);
        fused_stage<true ><<<dim3(1024), dim3(256), 0, stream>>>(
            edge, x, nullptr, nullptr,
            w_t + 0*WSZ, w_t + 1*WSZ, b_e1, b_pac1,
            nullptr, nullptr, res_edge1_t, res_sr1_t, nullptr, nullptr);
        fused_stage<false><<<dim3(1024), dim3(256), 0, stream>>>(
            nullptr, nullptr, res_edge1_t, res_sr1_t,
            w_t + 2*WSZ, w_t + 3*WSZ, b_e2, b_pac2,
            edge, x, nullptr, nullptr, out_edge, out_sr);
    }
}